// Round 1
// 546.550 us; speedup vs baseline: 1.0782x; 1.0782x over previous
//
#include <hip/hip_runtime.h>
#include <hip/hip_bf16.h>

// ---------------- problem constants ----------------
#define CC 192
#define NHEADS 6
#define HDIM 32
#define NTOK 49
#define NWIN 2048
#define MTOK 100352      // NWIN * NTOK
#define HIDDEN 768

typedef __hip_bfloat16 bf16;
typedef __attribute__((ext_vector_type(8))) short short8;
typedef __attribute__((ext_vector_type(4))) float f32x4;

// ---------------- weight fp32 -> bf16 conversion ----------------
__global__ __launch_bounds__(256) void k_wconv(
    const float* __restrict__ qw, const float* __restrict__ pw,
    const float* __restrict__ f1, const float* __restrict__ f2,
    bf16* __restrict__ o) {
  int i = blockIdx.x * 256 + threadIdx.x;
  if (i < 110592) o[i] = __float2bfloat16(qw[i]);
  else if (i < 147456) o[i] = __float2bfloat16(pw[i - 110592]);
  else if (i < 294912) o[i] = __float2bfloat16(f1[i - 147456]);
  else if (i < 442368) o[i] = __float2bfloat16(f2[i - 294912]);
}

// ---------------- bias6[h][49][49] = table[ridx[r*49+c]*6+h] -------------
__global__ __launch_bounds__(256) void k_bias(
    const float* __restrict__ table, const int* __restrict__ ridx,
    float* __restrict__ bias6) {
  int i = blockIdx.x * 256 + threadIdx.x;
  if (i >= 6 * 2401) return;
  int h = i / 2401, e = i - h * 2401;
  bias6[i] = table[ridx[e] * NHEADS + h];
}

// ---------------- LN1 + roll(-3,-3) + window partition ----------
__global__ __launch_bounds__(256) void k_ln1_part(
    const float* __restrict__ x, const float* __restrict__ g,
    const float* __restrict__ bta, bf16* __restrict__ xw) {
  int wv = blockIdx.x * 4 + (threadIdx.x >> 6);
  int lane = threadIdx.x & 63;
  int w = wv / NTOK, n = wv - w * NTOK;
  int b = w >> 6, wrem = w & 63;
  int hi = wrem >> 3, wi = wrem & 7;
  int i = n / 7, j = n - i * 7;
  int hsrc = hi * 7 + i + 3; if (hsrc >= 56) hsrc -= 56;
  int wsrc = wi * 7 + j + 3; if (wsrc >= 56) wsrc -= 56;
  const float* row = x + (size_t)((b * 56 + hsrc) * 56 + wsrc) * CC;
  float v0 = row[lane], v1 = row[lane + 64], v2 = row[lane + 128];
  float s = v0 + v1 + v2;
  for (int m = 32; m; m >>= 1) s += __shfl_xor(s, m, 64);
  float mu = s * (1.0f / 192.0f);
  float d0 = v0 - mu, d1 = v1 - mu, d2 = v2 - mu;
  float q = d0 * d0 + d1 * d1 + d2 * d2;
  for (int m = 32; m; m >>= 1) q += __shfl_xor(q, m, 64);
  float inv = rsqrtf(q * (1.0f / 192.0f) + 1e-5f);
  bf16* orow = xw + (size_t)wv * CC;
  orow[lane]       = __float2bfloat16(d0 * inv * g[lane]       + bta[lane]);
  orow[lane + 64]  = __float2bfloat16(d1 * inv * g[lane + 64]  + bta[lane + 64]);
  orow[lane + 128] = __float2bfloat16(d2 * inv * g[lane + 128] + bta[lane + 128]);
}

// ---------------- LN2 (fp32 in, bf16 out, row-major) ----------
__global__ __launch_bounds__(256) void k_ln2(
    const float* __restrict__ x1, const float* __restrict__ g,
    const float* __restrict__ bta, bf16* __restrict__ xn2) {
  int wv = blockIdx.x * 4 + (threadIdx.x >> 6);
  int lane = threadIdx.x & 63;
  const float* row = x1 + (size_t)wv * CC;
  float v0 = row[lane], v1 = row[lane + 64], v2 = row[lane + 128];
  float s = v0 + v1 + v2;
  for (int m = 32; m; m >>= 1) s += __shfl_xor(s, m, 64);
  float mu = s * (1.0f / 192.0f);
  float d0 = v0 - mu, d1 = v1 - mu, d2 = v2 - mu;
  float q = d0 * d0 + d1 * d1 + d2 * d2;
  for (int m = 32; m; m >>= 1) q += __shfl_xor(q, m, 64);
  float inv = rsqrtf(q * (1.0f / 192.0f) + 1e-5f);
  bf16* orow = xn2 + (size_t)wv * CC;
  orow[lane]       = __float2bfloat16(d0 * inv * g[lane]       + bta[lane]);
  orow[lane + 64]  = __float2bfloat16(d1 * inv * g[lane + 64]  + bta[lane + 64]);
  orow[lane + 128] = __float2bfloat16(d2 * inv * g[lane + 128] + bta[lane + 128]);
}

// ---------------- A-register-resident MFMA GEMM ----------------
// out[m,n] = A[m,:] . W[n,:] + bias[n]
// A rows live in registers (loaded ONCE from global); only B (64 x 192
// k-chunk) is staged in LDS, double-buffered, XOR-swizzled (row&7)<<4 on
// the byte offset (source pre-swizzled so global_load_lds dest stays linear).
// MODE 0: row-major bf16 out (qkv [M,576])
// MODE 1: proj + reverse/roll + residual (fp32 scatter)
// MODE 2: fc1 + GELU (bf16)   MODE 3: fc2 + residual (fp32)
// NT = N/64 n-tiles, KC = K/192 k-chunks, MF = m-frags per wave (BM = MF*64)
template <int MODE, int NT, int KC, int MF>
__global__ __launch_bounds__(256) void k_gemm_areg(
    const bf16* __restrict__ A, const bf16* __restrict__ W,
    const float* __restrict__ bias, void* __restrict__ out0,
    const void* __restrict__ aux) {
  constexpr int K = KC * 192;
  constexpr int N = NT * 64;
  __shared__ bf16 Bs[2][64 * 192];   // 2 x 24 KB
  const int tid = threadIdx.x;
  const int wave = tid >> 6, lane = tid & 63;
  const int grp = lane >> 4, rA = lane & 15;
  const int cq = grp, cn = rA;
  const int m0 = blockIdx.x * (MF * 64);
  const int mrow = m0 + wave * (MF * 16);

  // ---- A fragments: global -> regs, exactly once ----
  short8 areg[MF][KC * 6];
#pragma unroll
  for (int mt = 0; mt < MF; ++mt) {
    const bf16* arow = A + (size_t)(mrow + mt * 16 + rA) * K + grp * 8;
#pragma unroll
    for (int kt = 0; kt < KC * 6; ++kt)
      areg[mt][kt] = *(const short8*)(arow + kt * 32);
  }

  // ---- MODE 1: precompute scatter row offsets (n-independent) ----
  int rowoff[MF][4];
  if (MODE == 1) {
#pragma unroll
    for (int mt = 0; mt < MF; ++mt)
#pragma unroll
      for (int r = 0; r < 4; ++r) {
        int m = mrow + mt * 16 + cq * 4 + r;
        int w = m / 49, rr = m - w * 49;
        int b = w >> 6, wrem = w & 63;
        int hi = wrem >> 3, wi = wrem & 7;
        int ii = rr / 7, jj = rr - ii * 7;
        int hd = hi * 7 + ii + 3; if (hd >= 56) hd -= 56;
        int wd = wi * 7 + jj + 3; if (wd >= 56) wd -= 56;
        rowoff[mt][r] = ((b * 56 + hd) * 56 + wd) * CC;
      }
  }

  // ---- B stage: 6 x 16B chunks/thread, linear LDS dest, swizzled source --
  auto stage = [&](int buf, int nt, int kc) {
#pragma unroll
    for (int i = 0; i < 6; ++i) {
      int c = i * 256 + tid;                       // 16B chunk id, 24/row
      int row = c / 24;
      int cbl = ((c - row * 24) * 16) ^ ((row & 7) << 4);
      const char* src = (const char*)W +
          (size_t)(nt * 64 + row) * (K * 2) + kc * 384 + cbl;
      __builtin_amdgcn_global_load_lds(
          (const __attribute__((address_space(1))) void*)src,
          (__attribute__((address_space(3))) void*)((char*)&Bs[buf][0] + c * 16),
          16, 0, 0);
    }
  };
  stage(0, 0, 0);

  f32x4 acc[MF][4];
#pragma unroll
  for (int s = 0; s < NT * KC; ++s) {
    const int nt = s / KC, kc = s - nt * KC;
    const int cur = s & 1;
    __syncthreads();                          // drains cur's stage (vmcnt(0))
    if (s + 1 < NT * KC) stage(cur ^ 1, (s + 1) / KC, (s + 1) % KC);
    if (kc == 0) {
#pragma unroll
      for (int mt = 0; mt < MF; ++mt)
#pragma unroll
        for (int ntf = 0; ntf < 4; ++ntf)
          acc[mt][ntf] = (f32x4){0.f, 0.f, 0.f, 0.f};
    }
#pragma unroll
    for (int kt = 0; kt < 6; ++kt) {
      short8 b[4];
#pragma unroll
      for (int ntf = 0; ntf < 4; ++ntf) {
        int row = ntf * 16 + rA;
        int phys = row * 384 + ((kt * 64 + grp * 16) ^ ((row & 7) << 4));
        b[ntf] = *(const short8*)((const char*)&Bs[cur][0] + phys);
      }
#pragma unroll
      for (int mt = 0; mt < MF; ++mt)
#pragma unroll
        for (int ntf = 0; ntf < 4; ++ntf)
          acc[mt][ntf] = __builtin_amdgcn_mfma_f32_16x16x32_bf16(
              areg[mt][kc * 6 + kt], b[ntf], acc[mt][ntf], 0, 0, 0);
    }
    if (kc == KC - 1) {
      const int n0t = nt * 64;
      float bi[4];
#pragma unroll
      for (int ntf = 0; ntf < 4; ++ntf) bi[ntf] = bias[n0t + ntf * 16 + cn];
#pragma unroll
      for (int mt = 0; mt < MF; ++mt) {
#pragma unroll
        for (int r = 0; r < 4; ++r) {
          const int m = mrow + mt * 16 + cq * 4 + r;
#pragma unroll
          for (int ntf = 0; ntf < 4; ++ntf) {
            const int n = n0t + ntf * 16 + cn;
            float v = acc[mt][ntf][r] + bi[ntf];
            if (MODE == 0) {
              ((bf16*)out0)[(size_t)m * N + n] = __float2bfloat16(v);
            } else if (MODE == 2) {
              float ge = 0.5f * v * (1.0f + erff(v * 0.70710678118654752f));
              ((bf16*)out0)[(size_t)m * N + n] = __float2bfloat16(ge);
            } else if (MODE == 1) {
              float res = ((const float*)aux)[(size_t)rowoff[mt][r] + n];
              ((float*)out0)[(size_t)rowoff[mt][r] + n] = v + res;
            } else {
              float res = ((const float*)aux)[(size_t)m * CC + n];
              ((float*)out0)[(size_t)m * CC + n] = v + res;
            }
          }
        }
      }
    }
  }
}

// ---------------- MFMA attention: 1 wave per (window,head) ---------------
// qkv: [M,576] row-major; q cols [0,192), k [192,384), v [384,576)
__global__ __launch_bounds__(256) void k_attn_mfma(
    const bf16* __restrict__ qk, const float* __restrict__ bias6,
    bf16* __restrict__ ao) {
  __shared__ bf16 P[4][64 * 72];   // per-wave P,  36,864 B total
  __shared__ bf16 VT[4][32 * 72];  // per-wave V^T, 18,432 B total
  const int wave = threadIdx.x >> 6, lane = threadIdx.x & 63;
  const int wh = blockIdx.x * 4 + wave;
  const int w = wh / NHEADS, h = wh - w * NHEADS;
  const int rA = lane & 15, kq = (lane >> 4) * 8;
  const int grp = lane >> 4;

  const bf16* qbase = qk + (size_t)(w * 49) * 576 + h * HDIM + kq;

  // ---- load Q,K fragments + V rows straight from global ----
  short8 aq[4], bk[4], vrow[4];
#pragma unroll
  for (int t = 0; t < 4; ++t) {
    const bf16* rp = qbase + (size_t)(t * 16 + rA) * 576;
    aq[t] = *(const short8*)(rp);
    bk[t] = *(const short8*)(rp + 192);
    vrow[t] = *(const short8*)(rp + 384);
  }

  // ---- QK^T ----
  f32x4 S[4][4] = {};
#pragma unroll
  for (int mt = 0; mt < 4; ++mt)
#pragma unroll
    for (int nt = 0; nt < 4; ++nt)
      S[mt][nt] = __builtin_amdgcn_mfma_f32_16x16x32_bf16(
          aq[mt], bk[nt], S[mt][nt], 0, 0, 0);

  // ---- V transpose into LDS: VT[d][tok64], zero pad tok>=49 ----
  bf16* Vw = VT[wave];
  const bf16 zero = __float2bfloat16(0.0f);
#pragma unroll
  for (int t = 0; t < 4; ++t) {
    int tok = t * 16 + rA;
#pragma unroll
    for (int j = 0; j < 8; ++j)
      Vw[(kq + j) * 72 + tok] = (tok < 49) ? ((const bf16*)&vrow[t])[j] : zero;
  }

  // ---- softmax over rows (row in one 16-lane group + 4 nt regs) ----
  const float scale = 0.17677669529663687f;
  const float* bh = bias6 + h * 2401;
  float rs[4][4];
  bf16* Pw = P[wave];
#pragma unroll
  for (int mt = 0; mt < 4; ++mt) {
#pragma unroll
    for (int r = 0; r < 4; ++r) {
      int row = mt * 16 + grp * 4 + r;
      float val[4];
#pragma unroll
      for (int nt = 0; nt < 4; ++nt) {
        int c = nt * 16 + rA;
        float bv = (row < 49 && c < 49) ? bh[row * 49 + c] : 0.0f;
        val[nt] = (c < 49) ? (S[mt][nt][r] * scale + bv) : -1e30f;
      }
      float mx = fmaxf(fmaxf(val[0], val[1]), fmaxf(val[2], val[3]));
      for (int m2 = 1; m2 < 16; m2 <<= 1) mx = fmaxf(mx, __shfl_xor(mx, m2, 64));
      float sum = 0.0f;
#pragma unroll
      for (int nt = 0; nt < 4; ++nt) {
        float e = __expf(val[nt] - mx);
        val[nt] = e;
        sum += e;
      }
      for (int m2 = 1; m2 < 16; m2 <<= 1) sum += __shfl_xor(sum, m2, 64);
      rs[mt][r] = 1.0f / sum;
#pragma unroll
      for (int nt = 0; nt < 4; ++nt)
        Pw[row * 72 + nt * 16 + rA] = __float2bfloat16(val[nt]);
    }
  }
  __syncthreads();

  // ---- PV: A-frags from P-LDS, B-frags (V^T) from VT-LDS ----
  short8 bv[2][2];
#pragma unroll
  for (int ks = 0; ks < 2; ++ks)
#pragma unroll
    for (int nt = 0; nt < 2; ++nt)
      bv[ks][nt] = *(const short8*)&Vw[(nt * 16 + rA) * 72 + ks * 32 + kq];
  f32x4 O[4][2] = {};
#pragma unroll
  for (int mt = 0; mt < 4; ++mt) {
    short8 ap0 = *(const short8*)&Pw[(mt * 16 + rA) * 72 + kq];
    short8 ap1 = *(const short8*)&Pw[(mt * 16 + rA) * 72 + 32 + kq];
#pragma unroll
    for (int nt = 0; nt < 2; ++nt) {
      O[mt][nt] = __builtin_amdgcn_mfma_f32_16x16x32_bf16(ap0, bv[0][nt],
                                                          O[mt][nt], 0, 0, 0);
      O[mt][nt] = __builtin_amdgcn_mfma_f32_16x16x32_bf16(ap1, bv[1][nt],
                                                          O[mt][nt], 0, 0, 0);
    }
  }
  // ---- write O (rows m<49), normalized by row sums ----
#pragma unroll
  for (int mt = 0; mt < 4; ++mt) {
#pragma unroll
    for (int r = 0; r < 4; ++r) {
      int m = mt * 16 + grp * 4 + r;
      if (m < 49) {
        bf16* orow = ao + (size_t)(w * 49 + m) * CC + h * HDIM;
#pragma unroll
        for (int nt = 0; nt < 2; ++nt)
          orow[nt * 16 + rA] = __float2bfloat16(O[mt][nt][r] * rs[mt][r]);
      }
    }
  }
}

// ---------------- launcher ----------------
extern "C" void kernel_launch(void* const* d_in, const int* in_sizes, int n_in,
                              void* d_out, int out_size, void* d_ws, size_t ws_size,
                              hipStream_t stream) {
  const float* x        = (const float*)d_in[0];
  const float* norm1_g  = (const float*)d_in[1];
  const float* norm1_b  = (const float*)d_in[2];
  const float* qkv_w    = (const float*)d_in[3];
  const float* qkv_b    = (const float*)d_in[4];
  const float* proj_w   = (const float*)d_in[5];
  const float* proj_b   = (const float*)d_in[6];
  const float* rel_tab  = (const float*)d_in[7];
  const float* norm2_g  = (const float*)d_in[8];
  const float* norm2_b  = (const float*)d_in[9];
  const float* fc1_w    = (const float*)d_in[10];
  const float* fc1_b    = (const float*)d_in[11];
  const float* fc2_w    = (const float*)d_in[12];
  const float* fc2_b    = (const float*)d_in[13];
  const int*   rel_idx  = (const int*)d_in[14];
  float* out = (float*)d_out;

  // workspace layout (bytes):
  //   [0,           38,535,168)   slotA: xw -> ao -> xn2       (bf16 M*192)
  //   [38,535,168, 154,140,672)   qkv [M,576] bf16 (115,605,504 B; later hbuf)
  //   [154,140,672,155,025,408)   wbuf bf16 weights (884,736 B)
  //   [155,025,408,155,083,032)   bias6 fp32 (57,624 B)
  char* ws = (char*)d_ws;
  bf16*  xw    = (bf16*)ws;
  bf16*  qkb   = (bf16*)(ws + 38535168);
  bf16*  wbuf  = (bf16*)(ws + 154140672);
  float* bias6 = (float*)(ws + 155025408);
  bf16*  ao    = xw;
  bf16*  xn2   = xw;
  bf16*  hbuf  = qkb;   // 77,070,336 B needed, 115.6 MB available
  float* x1    = out;   // fp32 residual trunk lives in d_out
  bf16* wq = wbuf;
  bf16* wp = wbuf + 110592;
  bf16* w1 = wbuf + 147456;
  bf16* w2 = wbuf + 294912;

  k_wconv<<<1728, 256, 0, stream>>>(qkv_w, proj_w, fc1_w, fc2_w, wbuf);
  k_bias<<<57, 256, 0, stream>>>(rel_tab, rel_idx, bias6);
  k_ln1_part<<<MTOK / 4, 256, 0, stream>>>(x, norm1_g, norm1_b, xw);
  // qkv: [M,192] @ [576,192]^T -> [M,576] row-major bf16
  k_gemm_areg<0, 9, 1, 2><<<MTOK / 128, 256, 0, stream>>>(
      xw, wq, qkv_b, qkb, nullptr);
  k_attn_mfma<<<NWIN * NHEADS / 4, 256, 0, stream>>>(qkb, bias6, ao);
  // proj + reverse/roll + residual -> x1 (d_out, fp32 natural order)
  k_gemm_areg<1, 3, 1, 2><<<MTOK / 128, 256, 0, stream>>>(
      ao, wp, proj_b, x1, x);
  k_ln2<<<MTOK / 4, 256, 0, stream>>>(x1, norm2_g, norm2_b, xn2);
  const int MH = MTOK / 2;  // 50176
  for (int h = 0; h < 2; ++h) {
    size_t mo = (size_t)h * MH;
    k_gemm_areg<2, 12, 1, 2><<<MH / 128, 256, 0, stream>>>(
        xn2 + mo * CC, w1, fc1_b, hbuf, nullptr);
    k_gemm_areg<3, 3, 4, 1><<<MH / 64, 256, 0, stream>>>(
        hbuf, w2, fc2_b, out + mo * CC, x1 + mo * CC);
  }
}

// Round 2
// 473.491 us; speedup vs baseline: 1.2446x; 1.1543x over previous
//
#include <hip/hip_runtime.h>
#include <hip/hip_bf16.h>

// ---------------- problem constants ----------------
#define CC 192
#define NHEADS 6
#define HDIM 32
#define NTOK 49
#define NWIN 2048
#define MTOK 100352      // NWIN * NTOK
#define HIDDEN 768

typedef __hip_bfloat16 bf16;
typedef __attribute__((ext_vector_type(8))) short short8;
typedef __attribute__((ext_vector_type(4))) float f32x4;

// ---------------- weight fp32 -> bf16 conversion ----------------
__global__ __launch_bounds__(256) void k_wconv(
    const float* __restrict__ qw, const float* __restrict__ pw,
    const float* __restrict__ f1, const float* __restrict__ f2,
    bf16* __restrict__ o) {
  int i = blockIdx.x * 256 + threadIdx.x;
  if (i < 110592) o[i] = __float2bfloat16(qw[i]);
  else if (i < 147456) o[i] = __float2bfloat16(pw[i - 110592]);
  else if (i < 294912) o[i] = __float2bfloat16(f1[i - 147456]);
  else if (i < 442368) o[i] = __float2bfloat16(f2[i - 294912]);
}

// ---------------- bias6[h][49][49] = table[ridx[r*49+c]*6+h] -------------
__global__ __launch_bounds__(256) void k_bias(
    const float* __restrict__ table, const int* __restrict__ ridx,
    float* __restrict__ bias6) {
  int i = blockIdx.x * 256 + threadIdx.x;
  if (i >= 6 * 2401) return;
  int h = i / 2401, e = i - h * 2401;
  bias6[i] = table[ridx[e] * NHEADS + h];
}

// ---------------- A-register-resident MFMA GEMM ----------------
// out[m,n] = A'[m,:] . W[n,:] + bias[n], A' built in-register.
// MODE 0: A = x fp32, fused LN1 + roll(-3,-3) + window partition; bf16 out
// MODE 1: A = ao bf16; proj + window-reverse/roll + residual (fp32 scatter)
// MODE 2: A = x1 fp32, fused LN2; fc1 + tanh-GELU (bf16 out)
// MODE 3: A = hbuf bf16; fc2 + residual (fp32, in-place with aux==out ok)
// NT = N/64 n-tiles, KC = K/192 k-chunks, MF = m-frags per wave
template <int MODE, int NT, int KC, int MF>
__global__ __launch_bounds__(256) void k_gemm_areg(
    const void* __restrict__ Ap, const bf16* __restrict__ W,
    const float* __restrict__ bias, void* __restrict__ out0,
    const void* __restrict__ aux, const float* __restrict__ lng,
    const float* __restrict__ lnb) {
  constexpr int K = KC * 192;
  constexpr int N = NT * 64;
  __shared__ bf16 Bs[2][64 * 192];   // 2 x 24 KB
  const int tid = threadIdx.x;
  const int wave = tid >> 6, lane = tid & 63;
  const int grp = lane >> 4, rA = lane & 15;
  const int cq = grp, cn = rA;
  const int m0 = blockIdx.x * (MF * 64);
  const int mrow = m0 + wave * (MF * 16);

  // ---- A fragments: global -> regs, exactly once ----
  short8 areg[MF][KC * 6];
  if constexpr (MODE == 1 || MODE == 3) {
#pragma unroll
    for (int mt = 0; mt < MF; ++mt) {
      const bf16* arow =
          (const bf16*)Ap + (size_t)(mrow + mt * 16 + rA) * K + grp * 8;
#pragma unroll
      for (int kt = 0; kt < KC * 6; ++kt)
        areg[mt][kt] = *(const short8*)(arow + kt * 32);
    }
  } else {
    // fp32 input + fused LayerNorm (K == 192, KC == 1).
    // Each row is held by the 4 lanes sharing rA (grp 0..3, 48 floats each).
#pragma unroll
    for (int mt = 0; mt < MF; ++mt) {
      int m = mrow + mt * 16 + rA;
      const float* rowp;
      if constexpr (MODE == 0) {
        int w = m / 49, n = m - w * 49;
        int b = w >> 6, wrem = w & 63;
        int hi = wrem >> 3, wi = wrem & 7;
        int ii = n / 7, jj = n - ii * 7;
        int hs = hi * 7 + ii + 3; if (hs >= 56) hs -= 56;
        int wsc = wi * 7 + jj + 3; if (wsc >= 56) wsc -= 56;
        rowp = (const float*)Ap + (size_t)((b * 56 + hs) * 56 + wsc) * CC;
      } else {
        rowp = (const float*)Ap + (size_t)m * CC;
      }
      f32x4 xv[12];
#pragma unroll
      for (int kt = 0; kt < 6; ++kt) {
        xv[2 * kt]     = *(const f32x4*)(rowp + kt * 32 + grp * 8);
        xv[2 * kt + 1] = *(const f32x4*)(rowp + kt * 32 + grp * 8 + 4);
      }
      float s = 0.0f;
#pragma unroll
      for (int i = 0; i < 12; ++i)
#pragma unroll
        for (int j = 0; j < 4; ++j) s += xv[i][j];
      s += __shfl_xor(s, 16, 64);
      s += __shfl_xor(s, 32, 64);
      float mu = s * (1.0f / 192.0f);
      float q = 0.0f;
#pragma unroll
      for (int i = 0; i < 12; ++i)
#pragma unroll
        for (int j = 0; j < 4; ++j) {
          float d = xv[i][j] - mu;
          q += d * d;
        }
      q += __shfl_xor(q, 16, 64);
      q += __shfl_xor(q, 32, 64);
      float inv = rsqrtf(q * (1.0f / 192.0f) + 1e-5f);
#pragma unroll
      for (int kt = 0; kt < 6; ++kt) {
        short8 t;
#pragma unroll
        for (int j = 0; j < 8; ++j) {
          int col = kt * 32 + grp * 8 + j;
          float xval = xv[2 * kt + (j >> 2)][j & 3];
          float val = (xval - mu) * inv * lng[col] + lnb[col];
          bf16 hb = __float2bfloat16(val);
          t[j] = *reinterpret_cast<short*>(&hb);
        }
        areg[mt][kt] = t;
      }
    }
  }

  // ---- MODE 1: precompute scatter row offsets (n-independent) ----
  int rowoff[MF][4];
  if constexpr (MODE == 1) {
#pragma unroll
    for (int mt = 0; mt < MF; ++mt)
#pragma unroll
      for (int r = 0; r < 4; ++r) {
        int m = mrow + mt * 16 + cq * 4 + r;
        int w = m / 49, rr = m - w * 49;
        int b = w >> 6, wrem = w & 63;
        int hi = wrem >> 3, wi = wrem & 7;
        int ii = rr / 7, jj = rr - ii * 7;
        int hd = hi * 7 + ii + 3; if (hd >= 56) hd -= 56;
        int wd = wi * 7 + jj + 3; if (wd >= 56) wd -= 56;
        rowoff[mt][r] = ((b * 56 + hd) * 56 + wd) * CC;
      }
  }

  // ---- B stage: 6 x 16B chunks/thread, linear LDS dest, swizzled source --
  auto stage = [&](int buf, int nt, int kc) {
#pragma unroll
    for (int i = 0; i < 6; ++i) {
      int c = i * 256 + tid;                       // 16B chunk id, 24/row
      int row = c / 24;
      int cbl = ((c - row * 24) * 16) ^ ((row & 7) << 4);
      const char* src = (const char*)W +
          (size_t)(nt * 64 + row) * (K * 2) + kc * 384 + cbl;
      __builtin_amdgcn_global_load_lds(
          (const __attribute__((address_space(1))) void*)src,
          (__attribute__((address_space(3))) void*)((char*)&Bs[buf][0] + c * 16),
          16, 0, 0);
    }
  };
  stage(0, 0, 0);

  f32x4 acc[MF][4];
#pragma unroll
  for (int s = 0; s < NT * KC; ++s) {
    const int nt = s / KC, kc = s - nt * KC;
    const int cur = s & 1;
    __syncthreads();                          // drains cur's stage (vmcnt(0))
    if (s + 1 < NT * KC) stage(cur ^ 1, (s + 1) / KC, (s + 1) % KC);
    if (kc == 0) {
#pragma unroll
      for (int mt = 0; mt < MF; ++mt)
#pragma unroll
        for (int ntf = 0; ntf < 4; ++ntf)
          acc[mt][ntf] = (f32x4){0.f, 0.f, 0.f, 0.f};
    }
#pragma unroll
    for (int kt = 0; kt < 6; ++kt) {
      short8 b[4];
#pragma unroll
      for (int ntf = 0; ntf < 4; ++ntf) {
        int row = ntf * 16 + rA;
        int phys = row * 384 + ((kt * 64 + grp * 16) ^ ((row & 7) << 4));
        b[ntf] = *(const short8*)((const char*)&Bs[cur][0] + phys);
      }
#pragma unroll
      for (int mt = 0; mt < MF; ++mt)
#pragma unroll
        for (int ntf = 0; ntf < 4; ++ntf)
          acc[mt][ntf] = __builtin_amdgcn_mfma_f32_16x16x32_bf16(
              areg[mt][kc * 6 + kt], b[ntf], acc[mt][ntf], 0, 0, 0);
    }
    if (kc == KC - 1) {
      const int n0t = nt * 64;
      float bi[4];
#pragma unroll
      for (int ntf = 0; ntf < 4; ++ntf) bi[ntf] = bias[n0t + ntf * 16 + cn];
#pragma unroll
      for (int mt = 0; mt < MF; ++mt) {
#pragma unroll
        for (int r = 0; r < 4; ++r) {
          const int m = mrow + mt * 16 + cq * 4 + r;
#pragma unroll
          for (int ntf = 0; ntf < 4; ++ntf) {
            const int n = n0t + ntf * 16 + cn;
            float v = acc[mt][ntf][r] + bi[ntf];
            if constexpr (MODE == 0) {
              ((bf16*)out0)[(size_t)m * N + n] = __float2bfloat16(v);
            } else if constexpr (MODE == 2) {
              // tanh-form GELU: 0.5v(1+tanh(0.79788456(v+0.044715 v^3)))
              float u2 = 2.0f * v * (0.7978845608f + 0.0356774081f * v * v);
              float t = 1.0f - 2.0f / (1.0f + __expf(u2));
              float ge = 0.5f * v * (1.0f + t);
              ((bf16*)out0)[(size_t)m * N + n] = __float2bfloat16(ge);
            } else if constexpr (MODE == 1) {
              float res = ((const float*)aux)[(size_t)rowoff[mt][r] + n];
              ((float*)out0)[(size_t)rowoff[mt][r] + n] = v + res;
            } else {
              float res = ((const float*)aux)[(size_t)m * CC + n];
              ((float*)out0)[(size_t)m * CC + n] = v + res;
            }
          }
        }
      }
    }
  }
}

// ---------------- MFMA attention: 1 wave per (window,head) ---------------
// qkv: [M,576] row-major; q cols [0,192), k [192,384), v [384,576)
__global__ __launch_bounds__(256) void k_attn_mfma(
    const bf16* __restrict__ qk, const float* __restrict__ bias6,
    bf16* __restrict__ ao) {
  __shared__ bf16 P[4][64 * 72];   // per-wave P,  36,864 B total
  __shared__ bf16 VT[4][32 * 72];  // per-wave V^T, 18,432 B total
  const int wave = threadIdx.x >> 6, lane = threadIdx.x & 63;
  const int wh = blockIdx.x * 4 + wave;
  const int w = wh / NHEADS, h = wh - w * NHEADS;
  const int rA = lane & 15, kq = (lane >> 4) * 8;
  const int grp = lane >> 4;

  const bf16* qbase = qk + (size_t)(w * 49) * 576 + h * HDIM + kq;

  // ---- load Q,K fragments + V rows straight from global ----
  short8 aq[4], bk[4], vrow[4];
#pragma unroll
  for (int t = 0; t < 4; ++t) {
    const bf16* rp = qbase + (size_t)(t * 16 + rA) * 576;
    aq[t] = *(const short8*)(rp);
    bk[t] = *(const short8*)(rp + 192);
    vrow[t] = *(const short8*)(rp + 384);
  }

  // ---- QK^T ----
  f32x4 S[4][4] = {};
#pragma unroll
  for (int mt = 0; mt < 4; ++mt)
#pragma unroll
    for (int nt = 0; nt < 4; ++nt)
      S[mt][nt] = __builtin_amdgcn_mfma_f32_16x16x32_bf16(
          aq[mt], bk[nt], S[mt][nt], 0, 0, 0);

  // ---- V transpose into LDS: VT[d][tok64], zero pad tok>=49 ----
  bf16* Vw = VT[wave];
  const bf16 zero = __float2bfloat16(0.0f);
#pragma unroll
  for (int t = 0; t < 4; ++t) {
    int tok = t * 16 + rA;
#pragma unroll
    for (int j = 0; j < 8; ++j)
      Vw[(kq + j) * 72 + tok] = (tok < 49) ? ((const bf16*)&vrow[t])[j] : zero;
  }

  // ---- softmax over rows (row in one 16-lane group + 4 nt regs) ----
  const float scale = 0.17677669529663687f;
  const float* bh = bias6 + h * 2401;
  float rs[4][4];
  bf16* Pw = P[wave];
#pragma unroll
  for (int mt = 0; mt < 4; ++mt) {
#pragma unroll
    for (int r = 0; r < 4; ++r) {
      int row = mt * 16 + grp * 4 + r;
      float val[4];
#pragma unroll
      for (int nt = 0; nt < 4; ++nt) {
        int c = nt * 16 + rA;
        float bv = (row < 49 && c < 49) ? bh[row * 49 + c] : 0.0f;
        val[nt] = (c < 49) ? (S[mt][nt][r] * scale + bv) : -1e30f;
      }
      float mx = fmaxf(fmaxf(val[0], val[1]), fmaxf(val[2], val[3]));
      for (int m2 = 1; m2 < 16; m2 <<= 1) mx = fmaxf(mx, __shfl_xor(mx, m2, 64));
      float sum = 0.0f;
#pragma unroll
      for (int nt = 0; nt < 4; ++nt) {
        float e = __expf(val[nt] - mx);
        val[nt] = e;
        sum += e;
      }
      for (int m2 = 1; m2 < 16; m2 <<= 1) sum += __shfl_xor(sum, m2, 64);
      rs[mt][r] = 1.0f / sum;
#pragma unroll
      for (int nt = 0; nt < 4; ++nt)
        Pw[row * 72 + nt * 16 + rA] = __float2bfloat16(val[nt]);
    }
  }
  __syncthreads();

  // ---- PV: A-frags from P-LDS, B-frags (V^T) from VT-LDS ----
  short8 bv[2][2];
#pragma unroll
  for (int ks = 0; ks < 2; ++ks)
#pragma unroll
    for (int nt = 0; nt < 2; ++nt)
      bv[ks][nt] = *(const short8*)&Vw[(nt * 16 + rA) * 72 + ks * 32 + kq];
  f32x4 O[4][2] = {};
#pragma unroll
  for (int mt = 0; mt < 4; ++mt) {
    short8 ap0 = *(const short8*)&Pw[(mt * 16 + rA) * 72 + kq];
    short8 ap1 = *(const short8*)&Pw[(mt * 16 + rA) * 72 + 32 + kq];
#pragma unroll
    for (int nt = 0; nt < 2; ++nt) {
      O[mt][nt] = __builtin_amdgcn_mfma_f32_16x16x32_bf16(ap0, bv[0][nt],
                                                          O[mt][nt], 0, 0, 0);
      O[mt][nt] = __builtin_amdgcn_mfma_f32_16x16x32_bf16(ap1, bv[1][nt],
                                                          O[mt][nt], 0, 0, 0);
    }
  }
  // ---- write O (rows m<49), normalized by row sums ----
#pragma unroll
  for (int mt = 0; mt < 4; ++mt) {
#pragma unroll
    for (int r = 0; r < 4; ++r) {
      int m = mt * 16 + grp * 4 + r;
      if (m < 49) {
        bf16* orow = ao + (size_t)(w * 49 + m) * CC + h * HDIM;
#pragma unroll
        for (int nt = 0; nt < 2; ++nt)
          orow[nt * 16 + rA] = __float2bfloat16(O[mt][nt][r] * rs[mt][r]);
      }
    }
  }
}

// ---------------- launcher ----------------
extern "C" void kernel_launch(void* const* d_in, const int* in_sizes, int n_in,
                              void* d_out, int out_size, void* d_ws, size_t ws_size,
                              hipStream_t stream) {
  const float* x        = (const float*)d_in[0];
  const float* norm1_g  = (const float*)d_in[1];
  const float* norm1_b  = (const float*)d_in[2];
  const float* qkv_w    = (const float*)d_in[3];
  const float* qkv_b    = (const float*)d_in[4];
  const float* proj_w   = (const float*)d_in[5];
  const float* proj_b   = (const float*)d_in[6];
  const float* rel_tab  = (const float*)d_in[7];
  const float* norm2_g  = (const float*)d_in[8];
  const float* norm2_b  = (const float*)d_in[9];
  const float* fc1_w    = (const float*)d_in[10];
  const float* fc1_b    = (const float*)d_in[11];
  const float* fc2_w    = (const float*)d_in[12];
  const float* fc2_b    = (const float*)d_in[13];
  const int*   rel_idx  = (const int*)d_in[14];
  float* out = (float*)d_out;

  const size_t SZ_QKB = 115605504ull;   // M*576*2
  const size_t SZ_HBF = 154140672ull;   // M*768*2
  const size_t SZ_AO  = 38535168ull;    // M*192*2
  const size_t SZ_WB  = 884736ull;
  const size_t SZ_B6  = 57624ull;
  const bool fullM = ws_size >= SZ_HBF + SZ_AO + SZ_WB + SZ_B6;

  char* ws = (char*)d_ws;
  bf16 *qkb, *ao, *wbuf, *hbuf;
  float* bias6;
  if (fullM) {
    // [0, 154.1M): qkb (115.6M) then reused as full hbuf (154.1M)
    qkb   = (bf16*)ws;
    hbuf  = (bf16*)ws;
    ao    = (bf16*)(ws + SZ_HBF);
    wbuf  = (bf16*)(ws + SZ_HBF + SZ_AO);
    bias6 = (float*)(ws + SZ_HBF + SZ_AO + SZ_WB);
  } else {
    // [0, 115.6M): qkb, reused as half hbuf (77.1M)
    qkb   = (bf16*)ws;
    hbuf  = (bf16*)ws;
    ao    = (bf16*)(ws + SZ_QKB);
    wbuf  = (bf16*)(ws + SZ_QKB + SZ_AO);
    bias6 = (float*)(ws + SZ_QKB + SZ_AO + SZ_WB);
  }
  float* x1 = out;   // fp32 residual trunk lives in d_out
  bf16* wq = wbuf;
  bf16* wp = wbuf + 110592;
  bf16* w1 = wbuf + 147456;
  bf16* w2 = wbuf + 294912;

  k_wconv<<<1728, 256, 0, stream>>>(qkv_w, proj_w, fc1_w, fc2_w, wbuf);
  k_bias<<<57, 256, 0, stream>>>(rel_tab, rel_idx, bias6);
  // qkv with fused LN1 + roll/partition: x fp32 -> qkb [M,576] bf16
  k_gemm_areg<0, 9, 1, 1><<<MTOK / 64, 256, 0, stream>>>(
      x, wq, qkv_b, qkb, nullptr, norm1_g, norm1_b);
  k_attn_mfma<<<NWIN * NHEADS / 4, 256, 0, stream>>>(qkb, bias6, ao);
  // proj + reverse/roll + residual -> x1 (d_out, fp32 natural order)
  k_gemm_areg<1, 3, 1, 2><<<MTOK / 128, 256, 0, stream>>>(
      ao, wp, proj_b, x1, x, nullptr, nullptr);
  if (fullM) {
    // fc1 with fused LN2: x1 fp32 -> hbuf [M,768] bf16 (GELU)
    k_gemm_areg<2, 12, 1, 1><<<MTOK / 64, 256, 0, stream>>>(
        x1, w1, fc1_b, hbuf, nullptr, norm2_g, norm2_b);
    // fc2 + residual (in-place RMW on out, same element per thread)
    k_gemm_areg<3, 3, 4, 1><<<MTOK / 64, 256, 0, stream>>>(
        hbuf, w2, fc2_b, out, x1, nullptr, nullptr);
  } else {
    const int MH = MTOK / 2;  // 50176
    for (int h = 0; h < 2; ++h) {
      size_t mo = (size_t)h * MH;
      k_gemm_areg<2, 12, 1, 1><<<MH / 64, 256, 0, stream>>>(
          x1 + mo * CC, w1, fc1_b, hbuf, nullptr, norm2_g, norm2_b);
      k_gemm_areg<3, 3, 4, 1><<<MH / 64, 256, 0, stream>>>(
          hbuf, w2, fc2_b, out + mo * CC, x1 + mo * CC, nullptr, nullptr);
    }
  }
}

// Round 3
// 451.863 us; speedup vs baseline: 1.3041x; 1.0479x over previous
//
#include <hip/hip_runtime.h>
#include <hip/hip_bf16.h>

// ---------------- problem constants ----------------
#define CC 192
#define NHEADS 6
#define HDIM 32
#define NTOK 49
#define NWIN 2048
#define MTOK 100352      // NWIN * NTOK
#define HIDDEN 768

typedef __hip_bfloat16 bf16;
typedef __attribute__((ext_vector_type(8))) short short8;
typedef __attribute__((ext_vector_type(4))) float f32x4;

// ---------------- weight fp32 -> bf16 conversion ----------------
__global__ __launch_bounds__(256) void k_wconv(
    const float* __restrict__ qw, const float* __restrict__ pw,
    const float* __restrict__ f1, const float* __restrict__ f2,
    bf16* __restrict__ o) {
  int i = blockIdx.x * 256 + threadIdx.x;
  if (i < 110592) o[i] = __float2bfloat16(qw[i]);
  else if (i < 147456) o[i] = __float2bfloat16(pw[i - 110592]);
  else if (i < 294912) o[i] = __float2bfloat16(f1[i - 147456]);
  else if (i < 442368) o[i] = __float2bfloat16(f2[i - 294912]);
}

// ---------------- bias6[h][49][49] = table[ridx[r*49+c]*6+h] -------------
__global__ __launch_bounds__(256) void k_bias(
    const float* __restrict__ table, const int* __restrict__ ridx,
    float* __restrict__ bias6) {
  int i = blockIdx.x * 256 + threadIdx.x;
  if (i >= 6 * 2401) return;
  int h = i / 2401, e = i - h * 2401;
  bias6[i] = table[ridx[e] * NHEADS + h];
}

// ---------------- A-register-resident MFMA GEMM ----------------
// MODE 0: A = x fp32, fused LN1 + roll(-3,-3) + window partition; bf16 out
// MODE 1: A = ao bf16; proj + window-reverse/roll + residual (fp32 scatter)
template <int MODE, int NT, int KC, int MF>
__global__ __launch_bounds__(256) void k_gemm_areg(
    const void* __restrict__ Ap, const bf16* __restrict__ W,
    const float* __restrict__ bias, void* __restrict__ out0,
    const void* __restrict__ aux, const float* __restrict__ lng,
    const float* __restrict__ lnb) {
  constexpr int K = KC * 192;
  constexpr int N = NT * 64;
  __shared__ bf16 Bs[2][64 * 192];   // 2 x 24 KB
  const int tid = threadIdx.x;
  const int wave = tid >> 6, lane = tid & 63;
  const int grp = lane >> 4, rA = lane & 15;
  const int cq = grp, cn = rA;
  const int m0 = blockIdx.x * (MF * 64);
  const int mrow = m0 + wave * (MF * 16);

  // ---- A fragments: global -> regs, exactly once ----
  short8 areg[MF][KC * 6];
  if constexpr (MODE == 1) {
#pragma unroll
    for (int mt = 0; mt < MF; ++mt) {
      const bf16* arow =
          (const bf16*)Ap + (size_t)(mrow + mt * 16 + rA) * K + grp * 8;
#pragma unroll
      for (int kt = 0; kt < KC * 6; ++kt)
        areg[mt][kt] = *(const short8*)(arow + kt * 32);
    }
  } else {
    // fp32 input + fused LayerNorm + roll/partition (K == 192).
#pragma unroll
    for (int mt = 0; mt < MF; ++mt) {
      int m = mrow + mt * 16 + rA;
      int w = m / 49, n = m - w * 49;
      int b = w >> 6, wrem = w & 63;
      int hi = wrem >> 3, wi = wrem & 7;
      int ii = n / 7, jj = n - ii * 7;
      int hs = hi * 7 + ii + 3; if (hs >= 56) hs -= 56;
      int wsc = wi * 7 + jj + 3; if (wsc >= 56) wsc -= 56;
      const float* rowp =
          (const float*)Ap + (size_t)((b * 56 + hs) * 56 + wsc) * CC;
      f32x4 xv[12];
#pragma unroll
      for (int kt = 0; kt < 6; ++kt) {
        xv[2 * kt]     = *(const f32x4*)(rowp + kt * 32 + grp * 8);
        xv[2 * kt + 1] = *(const f32x4*)(rowp + kt * 32 + grp * 8 + 4);
      }
      float s = 0.0f;
#pragma unroll
      for (int i = 0; i < 12; ++i)
#pragma unroll
        for (int j = 0; j < 4; ++j) s += xv[i][j];
      s += __shfl_xor(s, 16, 64);
      s += __shfl_xor(s, 32, 64);
      float mu = s * (1.0f / 192.0f);
      float q = 0.0f;
#pragma unroll
      for (int i = 0; i < 12; ++i)
#pragma unroll
        for (int j = 0; j < 4; ++j) {
          float d = xv[i][j] - mu;
          q += d * d;
        }
      q += __shfl_xor(q, 16, 64);
      q += __shfl_xor(q, 32, 64);
      float inv = rsqrtf(q * (1.0f / 192.0f) + 1e-5f);
#pragma unroll
      for (int kt = 0; kt < 6; ++kt) {
        short8 t;
#pragma unroll
        for (int j = 0; j < 8; ++j) {
          int col = kt * 32 + grp * 8 + j;
          float xval = xv[2 * kt + (j >> 2)][j & 3];
          float val = (xval - mu) * inv * lng[col] + lnb[col];
          bf16 hb = __float2bfloat16(val);
          t[j] = *reinterpret_cast<short*>(&hb);
        }
        areg[mt][kt] = t;
      }
    }
  }

  // ---- MODE 1: precompute scatter row offsets (n-independent) ----
  int rowoff[MF][4];
  if constexpr (MODE == 1) {
#pragma unroll
    for (int mt = 0; mt < MF; ++mt)
#pragma unroll
      for (int r = 0; r < 4; ++r) {
        int m = mrow + mt * 16 + cq * 4 + r;
        int w = m / 49, rr = m - w * 49;
        int b = w >> 6, wrem = w & 63;
        int hi = wrem >> 3, wi = wrem & 7;
        int ii = rr / 7, jj = rr - ii * 7;
        int hd = hi * 7 + ii + 3; if (hd >= 56) hd -= 56;
        int wd = wi * 7 + jj + 3; if (wd >= 56) wd -= 56;
        rowoff[mt][r] = ((b * 56 + hd) * 56 + wd) * CC;
      }
  }

  auto stage = [&](int buf, int nt, int kc) {
#pragma unroll
    for (int i = 0; i < 6; ++i) {
      int c = i * 256 + tid;                       // 16B chunk id, 24/row
      int row = c / 24;
      int cbl = ((c - row * 24) * 16) ^ ((row & 7) << 4);
      const char* src = (const char*)W +
          (size_t)(nt * 64 + row) * (K * 2) + kc * 384 + cbl;
      __builtin_amdgcn_global_load_lds(
          (const __attribute__((address_space(1))) void*)src,
          (__attribute__((address_space(3))) void*)((char*)&Bs[buf][0] + c * 16),
          16, 0, 0);
    }
  };
  stage(0, 0, 0);

  f32x4 acc[MF][4];
#pragma unroll
  for (int s = 0; s < NT * KC; ++s) {
    const int nt = s / KC, kc = s - nt * KC;
    const int cur = s & 1;
    __syncthreads();                          // drains cur's stage (vmcnt(0))
    if (s + 1 < NT * KC) stage(cur ^ 1, (s + 1) / KC, (s + 1) % KC);
    if (kc == 0) {
#pragma unroll
      for (int mt = 0; mt < MF; ++mt)
#pragma unroll
        for (int ntf = 0; ntf < 4; ++ntf)
          acc[mt][ntf] = (f32x4){0.f, 0.f, 0.f, 0.f};
    }
#pragma unroll
    for (int kt = 0; kt < 6; ++kt) {
      short8 b[4];
#pragma unroll
      for (int ntf = 0; ntf < 4; ++ntf) {
        int row = ntf * 16 + rA;
        int phys = row * 384 + ((kt * 64 + grp * 16) ^ ((row & 7) << 4));
        b[ntf] = *(const short8*)((const char*)&Bs[cur][0] + phys);
      }
#pragma unroll
      for (int mt = 0; mt < MF; ++mt)
#pragma unroll
        for (int ntf = 0; ntf < 4; ++ntf)
          acc[mt][ntf] = __builtin_amdgcn_mfma_f32_16x16x32_bf16(
              areg[mt][kc * 6 + kt], b[ntf], acc[mt][ntf], 0, 0, 0);
    }
    if (kc == KC - 1) {
      const int n0t = nt * 64;
      float bi[4];
#pragma unroll
      for (int ntf = 0; ntf < 4; ++ntf) bi[ntf] = bias[n0t + ntf * 16 + cn];
#pragma unroll
      for (int mt = 0; mt < MF; ++mt) {
#pragma unroll
        for (int r = 0; r < 4; ++r) {
          const int m = mrow + mt * 16 + cq * 4 + r;
#pragma unroll
          for (int ntf = 0; ntf < 4; ++ntf) {
            const int n = n0t + ntf * 16 + cn;
            float v = acc[mt][ntf][r] + bi[ntf];
            if constexpr (MODE == 0) {
              ((bf16*)out0)[(size_t)m * N + n] = __float2bfloat16(v);
            } else {
              float res = ((const float*)aux)[(size_t)rowoff[mt][r] + n];
              ((float*)out0)[(size_t)rowoff[mt][r] + n] = v + res;
            }
          }
        }
      }
    }
  }
}

// ---------------- fused MLP: out += GELU(LN2(x1) @ W1^T + b1) @ W2^T + b2 --
// Per wave: 16 rows. Hidden never leaves the CU: per 64-col chunk,
// fc1-MFMA -> GELU -> per-wave LDS transpose tile -> fc2 accumulation.
// W1 chunks stage into Bs[0], W2 chunks into Bs[1] (2 barriers/chunk).
__global__ __launch_bounds__(256) void k_mlp(
    const float* __restrict__ x1, const bf16* __restrict__ W1,
    const bf16* __restrict__ W2, const float* __restrict__ b1,
    const float* __restrict__ b2, float* __restrict__ out,
    const float* __restrict__ lng, const float* __restrict__ lnb) {
  __shared__ bf16 Bs[2][64 * 192];   // buf0: W1 chunk (64x192), buf1: W2 chunk (192x64)
  __shared__ bf16 Hl[4][16 * 72];    // per-wave hidden transpose tile (row stride 144 B)
  const int tid = threadIdx.x;
  const int wave = tid >> 6, lane = tid & 63;
  const int grp = lane >> 4, rA = lane & 15;
  const int mrow = blockIdx.x * 64 + wave * 16;
  char* hb = (char*)&Hl[wave][0];

  // ---- LN2(x1) -> A fragments (row rA, k = kt*32 + grp*8) ----
  short8 areg[6];
  {
    const float* rowp = x1 + (size_t)(mrow + rA) * CC;
    f32x4 xv[12];
#pragma unroll
    for (int kt = 0; kt < 6; ++kt) {
      xv[2 * kt]     = *(const f32x4*)(rowp + kt * 32 + grp * 8);
      xv[2 * kt + 1] = *(const f32x4*)(rowp + kt * 32 + grp * 8 + 4);
    }
    float s = 0.0f;
#pragma unroll
    for (int i = 0; i < 12; ++i)
#pragma unroll
      for (int j = 0; j < 4; ++j) s += xv[i][j];
    s += __shfl_xor(s, 16, 64);
    s += __shfl_xor(s, 32, 64);
    float mu = s * (1.0f / 192.0f);
    float q = 0.0f;
#pragma unroll
    for (int i = 0; i < 12; ++i)
#pragma unroll
      for (int j = 0; j < 4; ++j) {
        float d = xv[i][j] - mu;
        q += d * d;
      }
    q += __shfl_xor(q, 16, 64);
    q += __shfl_xor(q, 32, 64);
    float inv = rsqrtf(q * (1.0f / 192.0f) + 1e-5f);
#pragma unroll
    for (int kt = 0; kt < 6; ++kt) {
      short8 t;
#pragma unroll
      for (int j = 0; j < 8; ++j) {
        int col = kt * 32 + grp * 8 + j;
        float xval = xv[2 * kt + (j >> 2)][j & 3];
        float val = (xval - mu) * inv * lng[col] + lnb[col];
        bf16 hbv = __float2bfloat16(val);
        t[j] = *reinterpret_cast<short*>(&hbv);
      }
      areg[kt] = t;
    }
  }

  // W1 chunk c: rows c*64..c*64+64 of [768][192], row stride 384 B, 24 slots
  auto stage1 = [&](int c) {
#pragma unroll
    for (int i = 0; i < 6; ++i) {
      int cc = i * 256 + tid;
      int row = cc / 24;
      int cbl = ((cc - row * 24) * 16) ^ ((row & 7) << 4);
      const char* src = (const char*)W1 + (size_t)(c * 64 + row) * 384 + cbl;
      __builtin_amdgcn_global_load_lds(
          (const __attribute__((address_space(1))) void*)src,
          (__attribute__((address_space(3))) void*)((char*)&Bs[0][0] + cc * 16),
          16, 0, 0);
    }
  };
  // W2 chunk c: all 192 rows of [192][768], k-cols c*64.., row stride 128 B, 8 slots
  auto stage2 = [&](int c) {
#pragma unroll
    for (int i = 0; i < 6; ++i) {
      int cc = i * 256 + tid;
      int row = cc >> 3, slot = cc & 7;
      int cbl = (slot * 16) ^ ((row & 7) << 4);
      const char* src = (const char*)W2 + (size_t)row * 1536 + c * 128 + cbl;
      __builtin_amdgcn_global_load_lds(
          (const __attribute__((address_space(1))) void*)src,
          (__attribute__((address_space(3))) void*)((char*)&Bs[1][0] + cc * 16),
          16, 0, 0);
    }
  };

  f32x4 acc2[12];
#pragma unroll
  for (int nf = 0; nf < 12; ++nf) acc2[nf] = (f32x4){0.f, 0.f, 0.f, 0.f};

  stage1(0);
  for (int c = 0; c < 12; ++c) {
    __syncthreads();                 // W1[c] landed; Bs[1] free
    stage2(c);                       // W2[c] flies under fc1 compute
    // ---- fc1 chunk: facc[ntf] = A @ W1chunk^T ----
    f32x4 fa[4] = {};
#pragma unroll
    for (int kt = 0; kt < 6; ++kt) {
      short8 bfr[4];
#pragma unroll
      for (int ntf = 0; ntf < 4; ++ntf) {
        int row = ntf * 16 + rA;
        int phys = row * 384 + ((kt * 64 + grp * 16) ^ ((row & 7) << 4));
        bfr[ntf] = *(const short8*)((const char*)&Bs[0][0] + phys);
      }
#pragma unroll
      for (int ntf = 0; ntf < 4; ++ntf)
        fa[ntf] = __builtin_amdgcn_mfma_f32_16x16x32_bf16(
            areg[kt], bfr[ntf], fa[ntf], 0, 0, 0);
    }
    // ---- +b1, GELU, write hidden tile (transposed access next) ----
#pragma unroll
    for (int ntf = 0; ntf < 4; ++ntf) {
      float b1v = b1[c * 64 + ntf * 16 + rA];
#pragma unroll
      for (int r = 0; r < 4; ++r) {
        float v = fa[ntf][r] + b1v;
        float u2 = 2.0f * v * (0.7978845608f + 0.0356774081f * v * v);
        float t = 1.0f - 2.0f / (1.0f + __expf(u2));
        float ge = 0.5f * v * (1.0f + t);
        int row = grp * 4 + r;
        int byte = (row * 144 + (ntf * 16 + rA) * 2) ^ ((row & 8) << 1);
        *(bf16*)(hb + byte) = __float2bfloat16(ge);
      }
    }
    __syncthreads();                 // W2[c] landed; Bs[0] free
    if (c + 1 < 12) stage1(c + 1);   // W1[c+1] flies under fc2 compute
    // ---- fc2 accumulate: acc2[nf] += h_chunk @ W2chunk^T ----
    short8 a2[2];
#pragma unroll
    for (int kt2 = 0; kt2 < 2; ++kt2)
      a2[kt2] = *(const short8*)(
          hb + ((rA * 144 + grp * 16 + kt2 * 64) ^ ((rA & 8) << 1)));
#pragma unroll
    for (int nf = 0; nf < 12; ++nf) {
      int row = nf * 16 + rA;
      int sw = (row & 7) << 4;
      short8 bw0 = *(const short8*)(
          (const char*)&Bs[1][0] + row * 128 + ((grp * 16) ^ sw));
      short8 bw1 = *(const short8*)(
          (const char*)&Bs[1][0] + row * 128 + ((64 + grp * 16) ^ sw));
      acc2[nf] = __builtin_amdgcn_mfma_f32_16x16x32_bf16(a2[0], bw0, acc2[nf], 0, 0, 0);
      acc2[nf] = __builtin_amdgcn_mfma_f32_16x16x32_bf16(a2[1], bw1, acc2[nf], 0, 0, 0);
    }
  }

  // ---- epilogue: out[m,n] += acc2 + b2 (residual RMW; out == x1) ----
#pragma unroll
  for (int nf = 0; nf < 12; ++nf) {
    float b2v = b2[nf * 16 + rA];
#pragma unroll
    for (int r = 0; r < 4; ++r) {
      int m = mrow + grp * 4 + r;
      size_t idx = (size_t)m * CC + nf * 16 + rA;
      out[idx] = out[idx] + acc2[nf][r] + b2v;
    }
  }
}

// ---------------- MFMA attention: 1 wave per (window,head) ---------------
__global__ __launch_bounds__(256) void k_attn_mfma(
    const bf16* __restrict__ qk, const float* __restrict__ bias6,
    bf16* __restrict__ ao) {
  __shared__ bf16 P[4][64 * 72];
  __shared__ bf16 VT[4][32 * 72];
  const int wave = threadIdx.x >> 6, lane = threadIdx.x & 63;
  const int wh = blockIdx.x * 4 + wave;
  const int w = wh / NHEADS, h = wh - w * NHEADS;
  const int rA = lane & 15, kq = (lane >> 4) * 8;
  const int grp = lane >> 4;

  const bf16* qbase = qk + (size_t)(w * 49) * 576 + h * HDIM + kq;

  short8 aq[4], bk[4], vrow[4];
#pragma unroll
  for (int t = 0; t < 4; ++t) {
    const bf16* rp = qbase + (size_t)(t * 16 + rA) * 576;
    aq[t] = *(const short8*)(rp);
    bk[t] = *(const short8*)(rp + 192);
    vrow[t] = *(const short8*)(rp + 384);
  }

  f32x4 S[4][4] = {};
#pragma unroll
  for (int mt = 0; mt < 4; ++mt)
#pragma unroll
    for (int nt = 0; nt < 4; ++nt)
      S[mt][nt] = __builtin_amdgcn_mfma_f32_16x16x32_bf16(
          aq[mt], bk[nt], S[mt][nt], 0, 0, 0);

  bf16* Vw = VT[wave];
  const bf16 zero = __float2bfloat16(0.0f);
#pragma unroll
  for (int t = 0; t < 4; ++t) {
    int tok = t * 16 + rA;
#pragma unroll
    for (int j = 0; j < 8; ++j)
      Vw[(kq + j) * 72 + tok] = (tok < 49) ? ((const bf16*)&vrow[t])[j] : zero;
  }

  const float scale = 0.17677669529663687f;
  const float* bh = bias6 + h * 2401;
  float rs[4][4];
  bf16* Pw = P[wave];
#pragma unroll
  for (int mt = 0; mt < 4; ++mt) {
#pragma unroll
    for (int r = 0; r < 4; ++r) {
      int row = mt * 16 + grp * 4 + r;
      float val[4];
#pragma unroll
      for (int nt = 0; nt < 4; ++nt) {
        int c = nt * 16 + rA;
        float bv = (row < 49 && c < 49) ? bh[row * 49 + c] : 0.0f;
        val[nt] = (c < 49) ? (S[mt][nt][r] * scale + bv) : -1e30f;
      }
      float mx = fmaxf(fmaxf(val[0], val[1]), fmaxf(val[2], val[3]));
      for (int m2 = 1; m2 < 16; m2 <<= 1) mx = fmaxf(mx, __shfl_xor(mx, m2, 64));
      float sum = 0.0f;
#pragma unroll
      for (int nt = 0; nt < 4; ++nt) {
        float e = __expf(val[nt] - mx);
        val[nt] = e;
        sum += e;
      }
      for (int m2 = 1; m2 < 16; m2 <<= 1) sum += __shfl_xor(sum, m2, 64);
      rs[mt][r] = 1.0f / sum;
#pragma unroll
      for (int nt = 0; nt < 4; ++nt)
        Pw[row * 72 + nt * 16 + rA] = __float2bfloat16(val[nt]);
    }
  }
  __syncthreads();

  short8 bv[2][2];
#pragma unroll
  for (int ks = 0; ks < 2; ++ks)
#pragma unroll
    for (int nt = 0; nt < 2; ++nt)
      bv[ks][nt] = *(const short8*)&Vw[(nt * 16 + rA) * 72 + ks * 32 + kq];
  f32x4 O[4][2] = {};
#pragma unroll
  for (int mt = 0; mt < 4; ++mt) {
    short8 ap0 = *(const short8*)&Pw[(mt * 16 + rA) * 72 + kq];
    short8 ap1 = *(const short8*)&Pw[(mt * 16 + rA) * 72 + 32 + kq];
#pragma unroll
    for (int nt = 0; nt < 2; ++nt) {
      O[mt][nt] = __builtin_amdgcn_mfma_f32_16x16x32_bf16(ap0, bv[0][nt],
                                                          O[mt][nt], 0, 0, 0);
      O[mt][nt] = __builtin_amdgcn_mfma_f32_16x16x32_bf16(ap1, bv[1][nt],
                                                          O[mt][nt], 0, 0, 0);
    }
  }
#pragma unroll
  for (int mt = 0; mt < 4; ++mt) {
#pragma unroll
    for (int r = 0; r < 4; ++r) {
      int m = mt * 16 + grp * 4 + r;
      if (m < 49) {
        bf16* orow = ao + (size_t)(w * 49 + m) * CC + h * HDIM;
#pragma unroll
        for (int nt = 0; nt < 2; ++nt)
          orow[nt * 16 + rA] = __float2bfloat16(O[mt][nt][r] * rs[mt][r]);
      }
    }
  }
}

// ---------------- launcher ----------------
extern "C" void kernel_launch(void* const* d_in, const int* in_sizes, int n_in,
                              void* d_out, int out_size, void* d_ws, size_t ws_size,
                              hipStream_t stream) {
  const float* x        = (const float*)d_in[0];
  const float* norm1_g  = (const float*)d_in[1];
  const float* norm1_b  = (const float*)d_in[2];
  const float* qkv_w    = (const float*)d_in[3];
  const float* qkv_b    = (const float*)d_in[4];
  const float* proj_w   = (const float*)d_in[5];
  const float* proj_b   = (const float*)d_in[6];
  const float* rel_tab  = (const float*)d_in[7];
  const float* norm2_g  = (const float*)d_in[8];
  const float* norm2_b  = (const float*)d_in[9];
  const float* fc1_w    = (const float*)d_in[10];
  const float* fc1_b    = (const float*)d_in[11];
  const float* fc2_w    = (const float*)d_in[12];
  const float* fc2_b    = (const float*)d_in[13];
  const int*   rel_idx  = (const int*)d_in[14];
  float* out = (float*)d_out;

  // workspace layout (bytes):
  //   [0,          115,605,504)  qkb [M,576] bf16
  //   [115,605,504,154,140,672)  ao  [M,192] bf16
  //   [154,140,672,155,025,408)  wbuf bf16 weights
  //   [155,025,408,155,083,032)  bias6 fp32
  char* ws = (char*)d_ws;
  bf16*  qkb   = (bf16*)ws;
  bf16*  ao    = (bf16*)(ws + 115605504);
  bf16*  wbuf  = (bf16*)(ws + 154140672);
  float* bias6 = (float*)(ws + 155025408);
  float* x1    = out;   // fp32 residual trunk lives in d_out
  bf16* wq = wbuf;
  bf16* wp = wbuf + 110592;
  bf16* w1 = wbuf + 147456;
  bf16* w2 = wbuf + 294912;

  k_wconv<<<1728, 256, 0, stream>>>(qkv_w, proj_w, fc1_w, fc2_w, wbuf);
  k_bias<<<57, 256, 0, stream>>>(rel_tab, rel_idx, bias6);
  // qkv with fused LN1 + roll/partition: x fp32 -> qkb [M,576] bf16
  k_gemm_areg<0, 9, 1, 1><<<MTOK / 64, 256, 0, stream>>>(
      x, wq, qkv_b, qkb, nullptr, norm1_g, norm1_b);
  k_attn_mfma<<<NWIN * NHEADS / 4, 256, 0, stream>>>(qkb, bias6, ao);
  // proj + reverse/roll + residual -> x1 (d_out, fp32 natural order)
  k_gemm_areg<1, 3, 1, 2><<<MTOK / 128, 256, 0, stream>>>(
      ao, wp, proj_b, x1, x, nullptr, nullptr);
  // fused MLP: out += GELU(LN2(x1) @ W1^T + b1) @ W2^T + b2
  k_mlp<<<MTOK / 64, 256, 0, stream>>>(
      x1, w1, w2, fc1_b, fc2_b, out, norm2_g, norm2_b);
}